// Round 10
// baseline (260.408 us; speedup 1.0000x reference)
//
#include <hip/hip_runtime.h>

// 4D conv (K=3^4, SAME P=1), bf16 MFMA implicit GEMM, ONE fused kernel.
//  phase 1: x -> xt[b][d0][p1(26)][h(2)][p2*p3(676)][8ci] bf16 (pad baked in),
//           W -> Wt[81][co][ci] bf16   (both in d_ws)
//  grid barrier (proven structure)
//  phase 2: XCD-chunked tiles; per tile <=3 bodies (k0); per body
//           [vmcnt(0)][s_barrier][af 27 loads][pin][stage(i+1)][pin][54 MFMA],
//           2 LDS slab buffers, 1 block/CU.
//  R9 lesson (counters): stage ran at ~500 GB/s because the out-store stream
//  (85 MB) write-allocates in the 4MB per-XCD L2 and evicts xt. THIS round:
//  non-temporal hints on all no-reuse streams (x loads, xt stores, out stores)
//  so L2 is reserved for xt stage re-reads + Wt. Everything else == R9.

#define D      24
#define D2_    (24*24)
#define D3_    (24*24*24)
#define D4_    (24*24*24*24)
#define CIN    16
#define COUT   32
#define NTHR   576          // 9 waves
#define GRID   256          // = #CUs; 1 block/CU resident -> grid barrier safe

#define ROW_USH   (2*676*8)       // 10816 ushorts per (b,d0,p1) row (21632 B)
#define SLAB_USH  (3*ROW_USH)     // 32448 ushorts = 64896 B per buffer
#define LDS_BYTES (2*SLAB_USH*2)  // 129792 B

#define XT_ELEMS  (2*24*26*26*26*16)
#define XT_BYTES  (XT_ELEMS*2)
#define WT_ELEMS  (81*32*16)
#define CNT_OFF_B (XT_BYTES + WT_ELEMS*2)
#define WS_NEED   (CNT_OFF_B + 64)

typedef __bf16 bf16x8 __attribute__((ext_vector_type(8)));
typedef float  f32x16 __attribute__((ext_vector_type(16)));
typedef unsigned short ushort_t;
typedef ushort_t ushort8 __attribute__((ext_vector_type(8)));
typedef ushort_t ushort4_ __attribute__((ext_vector_type(4)));

union u2b8 { ushort8 u; bf16x8 b; };

typedef const __attribute__((address_space(1))) unsigned int gu32;
typedef __attribute__((address_space(3))) unsigned int lu32;

__device__ inline ushort_t f2bf(float f) {
    union { float f; unsigned u; } x; x.f = f;
    unsigned r = x.u + 0x7FFFu + ((x.u >> 16) & 1u);   // RNE
    return (ushort_t)(r >> 16);
}

__global__ void __launch_bounds__(NTHR, 1) conv4d_fused(
    const float* __restrict__ x,
    const float* __restrict__ W,
    float* __restrict__ out,
    ushort_t* __restrict__ ws)
{
    extern __shared__ __align__(16) ushort_t lds[];   // 2 slab buffers

    ushort_t* xt = ws;
    ushort_t* Wt = ws + XT_BYTES / 2;
    unsigned* cnt = (unsigned*)((char*)ws + CNT_OFF_B);

    const int bk  = blockIdx.x;
    const int tid = threadIdx.x;

    // ---------------- phase 1: transpose/convert (NT in, NT out) ----------------
    {
        const long gtid = (long)bk * NTHR + tid;
        const long nthr = (long)GRID * NTHR;
        for (long u = gtid; u < XT_ELEMS / 8; u += nthr) {
            const int pp = (int)(u % 676);
            long t2 = u / 676;
            const int h  = (int)(t2 & 1); t2 >>= 1;
            const int p1 = (int)(t2 % 26); t2 /= 26;
            const int d0 = (int)(t2 % 24);
            const int b  = (int)(t2 / 24);
            const int p2 = pp / 26, p3 = pp - 26 * (pp / 26);
            const int r1 = p1 - 1, r2 = p2 - 1, r3 = p3 - 1;
            ushort8 v;
            if ((unsigned)r1 < 24u && (unsigned)r2 < 24u && (unsigned)r3 < 24u) {
                const float* xp = x + (long)(b * 16 + h * 8) * D4_
                                    + d0 * D3_ + r1 * D2_ + r2 * D + r3;
                #pragma unroll
                for (int c = 0; c < 8; ++c)
                    v[c] = f2bf(__builtin_nontemporal_load(xp + (long)c * D4_));
            } else {
                #pragma unroll
                for (int c = 0; c < 8; ++c) v[c] = 0;
            }
            __builtin_nontemporal_store(v, (ushort8*)&xt[u * 8]);
        }
        for (long i = gtid; i < WT_ELEMS; i += nthr) {
            const int tap = (int)(i >> 9);
            const int co  = (int)((i >> 4) & 31);
            const int ci  = (int)(i & 15);
            Wt[i] = f2bf(W[((long)co * 16 + ci) * 81 + tap]);
        }
    }

    // ---------------- grid barrier (proven structure) ----------------
    __threadfence();
    __syncthreads();
    if (tid == 0) {
        __hip_atomic_fetch_add(cnt, 1u, __ATOMIC_ACQ_REL, __HIP_MEMORY_SCOPE_AGENT);
        while (__hip_atomic_load(cnt, __ATOMIC_ACQUIRE, __HIP_MEMORY_SCOPE_AGENT)
               < (unsigned)GRID)
            __builtin_amdgcn_s_sleep(2);
    }
    __syncthreads();

    // ---------------- phase 2: pipelined implicit GEMM ----------------
    const int lane = tid & 63;
    const int wave = tid >> 6;          // 0..8
    const int col  = lane & 31;
    const int hi   = lane >> 5;

    int ppos0, ppos1, sbase0, sbase1;
    {
        const int pos0 = (wave * 2 + 0) * 32 + col;
        const int pos1 = (wave * 2 + 1) * 32 + col;
        ppos0 = pos0; ppos1 = pos1;
        sbase0 = (hi * 676 + (pos0 / D) * 26 + (pos0 % D)) * 8;
        sbase1 = (hi * 676 + (pos1 / D) * 26 + (pos1 % D)) * 8;
    }

    // XCD-chunked tile mapping: 1152 tiles = 8 XCDs x 144; 32 blocks per XCD.
    const int xcd  = bk & 7;
    const int slot = bk >> 3;

    for (int t = slot; t < 144; t += 32) {
        const int tile = xcd * 144 + t;
        const int b   = tile / 576;
        const int d01 = tile % 576;
        const int d0  = d01 / 24;
        const int d1  = d01 % 24;

        const int k0lo = (d0 == 0) ? 1 : 0;
        const int k0hi = (d0 == 23) ? 1 : 2;
        const int nb0  = k0hi - k0lo + 1;       // 2 or 3 bodies

        f32x16 acc0, acc1;
        #pragma unroll
        for (int r = 0; r < 16; ++r) { acc0[r] = 0.f; acc1[r] = 0.f; }

        // stage body i -> lds buffer (i&1): contiguous 64896 B copy.
        auto stage = [&](int i) {
            const int r0 = d0 + k0lo + i - 1;          // 0..23 by construction
            const ushort_t* src = xt + ((long)(b * 24 + r0) * 26 + d1) * ROW_USH;
            ushort_t* dst = lds + (i & 1) * SLAB_USH;
            #pragma unroll
            for (int j = 0; j < 8; ++j) {
                const int c = wave + 9 * j;
                if (c < 64) {
                    const bool act = (c < 63) | (lane < 24);
                    if (act)
                        __builtin_amdgcn_global_load_lds(
                            (gu32*)src + (c * 256 + lane * 4),
                            (lu32*)(dst + c * 512), 16, 0, 0);
                }
            }
        };

        auto loadaf = [&](bf16x8* af, const ushort_t* wb, int s) {
            const ushort_t* w = wb + s * 9 * 512;
            #pragma unroll
            for (int kc = 0; kc < 9; ++kc) {
                u2b8 cvt; cvt.u = *(const ushort8*)(w + kc * 512);
                af[kc] = cvt.b;
            }
        };

        // one k1 sub-phase: 9 taps x 2 N-tiles; tap offset = (k2*26+k3)*8
        #define SUBPHASE(AF, S)                                                 \
        {                                                                        \
            const ushort_t* sp0 = sbuf + (S) * ROW_USH + sbase0;                 \
            const ushort_t* sp1 = sbuf + (S) * ROW_USH + sbase1;                 \
            _Pragma("unroll")                                                    \
            for (int kc = 0; kc < 9; ++kc) {                                     \
                const int ko = ((kc / 3) * 26 + (kc % 3)) * 8;                   \
                u2b8 c0; c0.u = *(const ushort8*)(sp0 + ko);                     \
                acc0 = __builtin_amdgcn_mfma_f32_32x32x16_bf16(                  \
                           (AF)[kc], c0.b, acc0, 0, 0, 0);                       \
                u2b8 c1; c1.u = *(const ushort8*)(sp1 + ko);                     \
                acc1 = __builtin_amdgcn_mfma_f32_32x32x16_bf16(                  \
                           (AF)[kc], c1.b, acc1, 0, 0, 0);                       \
            }                                                                    \
        }

        stage(0);
        for (int i = 0; i < nb0; ++i) {
            // my stage(i) loads were the LAST vmem I issued -> vmcnt(0) waits
            // exactly for them (also retires prev tile's stores at i==0).
            asm volatile("s_waitcnt vmcnt(0)" ::: "memory");
            asm volatile("s_barrier" ::: "memory");

            const ushort_t* sbuf = lds + (i & 1) * SLAB_USH;
            const ushort_t* wb = Wt + (long)(k0lo + i) * 27 * 512
                                    + col * 16 + hi * 8;

            // af FIRST (L2-hot), then stage(i+1): af waits by later MFMAs
            // never force the in-flight stage to drain (in-order vmcnt).
            bf16x8 af0[9], af1[9], af2[9];
            loadaf(af0, wb, 0);
            loadaf(af1, wb, 1);
            loadaf(af2, wb, 2);
            asm volatile("" ::: "memory");   // pin: af issued before stage
            if (i + 1 < nb0) stage(i + 1);
            asm volatile("" ::: "memory");   // pin: MFMA/ds_reads after stage

            __builtin_amdgcn_s_setprio(1);
            SUBPHASE(af0, 0)
            SUBPHASE(af1, 1)
            SUBPHASE(af2, 2)
            __builtin_amdgcn_s_setprio(0);
        }
        #undef SUBPHASE

        // epilogue: row=co=(r&3)+8*(r>>2)+4*hi, col=pos  (non-temporal stores)
        float* ob = out + (long)b * COUT * D4_ + (long)d0 * D3_ + (long)d1 * D2_;
        #pragma unroll
        for (int r = 0; r < 16; ++r) {
            const int co = (r & 3) + 8 * (r >> 2) + 4 * hi;
            __builtin_nontemporal_store(acc0[r], &ob[(long)co * D4_ + ppos0]);
            __builtin_nontemporal_store(acc1[r], &ob[(long)co * D4_ + ppos1]);
        }
        // all waves done reading lds before next tile's stage(0) overwrites
        asm volatile("s_barrier" ::: "memory");
    }
}

// ===================== fallback (proven R4 kernel) =====================
__device__ inline int fswz(int f) { return f ^ ((f >> 3) & 7); }

__global__ __launch_bounds__(384) void conv4d_mfma_fb(
    const float* __restrict__ x,
    const float* __restrict__ W,
    float* __restrict__ out)
{
    __shared__ __align__(16) ushort_t slab[26 * 26 * CIN];
    __shared__ __align__(16) ushort_t agrp[9 * COUT * CIN];

    const int d01  = blockIdx.x;
    const int b    = blockIdx.y;
    const int d0   = d01 / D;
    const int d1   = d01 % D;
    const int tid  = threadIdx.x;
    const int lane = tid & 63;
    const int wave = tid >> 6;
    const int col  = lane & 31;
    const int hi   = lane >> 5;

    const int afbase = fswz(col * 2 + hi) * 8;
    int ppos[3], sbase[3];
    #pragma unroll
    for (int t = 0; t < 3; ++t) {
        int pos = (wave * 3 + t) * 32 + col;
        ppos[t]  = pos;
        sbase[t] = ((pos / D) * 26 + (pos % D)) * CIN + hi * 8;
    }

    f32x16 acc[3];
    #pragma unroll
    for (int t = 0; t < 3; ++t)
        #pragma unroll
        for (int r = 0; r < 16; ++r) acc[t][r] = 0.f;

    const float* xb = x + (long)b * CIN * D4_;

    for (int k0 = 0; k0 < 3; ++k0) {
        const int r0 = d0 + k0 - 1;
        if ((unsigned)r0 >= (unsigned)D) continue;
        for (int k1 = 0; k1 < 3; ++k1) {
            const int r1 = d1 + k1 - 1;
            if ((unsigned)r1 >= (unsigned)D) continue;

            __syncthreads();

            const float* xp = xb + (long)r0 * D3_ + (long)r1 * D2_;
            for (int idx = tid; idx < 26 * 26 * 2; idx += 384) {
                const int pidx = idx >> 1;
                const int h    = idx & 1;
                const int p2   = pidx / 26;
                const int p3   = pidx - p2 * 26;
                const int s2   = p2 - 1;
                const int s3   = p3 - 1;
                const bool in  = (unsigned)s2 < (unsigned)D &&
                                 (unsigned)s3 < (unsigned)D;
                const float* xs = xp + s2 * D + s3;
                ushort8 v;
                #pragma unroll
                for (int c = 0; c < 8; ++c) {
                    float f = in ? xs[(long)(h * 8 + c) * D4_] : 0.f;
                    v[c] = f2bf(f);
                }
                *(ushort8*)&slab[idx * 8] = v;
            }

            const int kw0 = k0 * 27 + k1 * 9;
            for (int u = tid; u < 9 * COUT * 4; u += 384) {
                const int tap = u >> 7;
                const int rem = u & 127;
                const int co  = rem >> 2;
                const int q   = rem & 3;
                const int ci0 = (q >> 1) * 8 + (q & 1) * 4;
                const float* wp = W + co * (CIN * 81) + kw0 + tap;
                ushort4_ v;
                #pragma unroll
                for (int c = 0; c < 4; ++c)
                    v[c] = f2bf(wp[(ci0 + c) * 81]);
                const int f  = co * 2 + (q >> 1);
                const int h2 = q & 1;
                *(ushort4_*)&agrp[tap * 512 + fswz(f) * 8 + h2 * 4] = v;
            }
            __syncthreads();

            bf16x8 af[9];
            #pragma unroll
            for (int kc = 0; kc < 9; ++kc) {
                u2b8 cvt;
                cvt.u = *(const ushort8*)&agrp[kc * 512 + afbase];
                af[kc] = cvt.b;
            }

            #pragma unroll
            for (int kc = 0; kc < 9; ++kc) {
                const int koff = ((kc / 3) * 26 + (kc % 3)) * CIN;
                #pragma unroll
                for (int t = 0; t < 3; ++t) {
                    u2b8 cvt;
                    cvt.u = *(const ushort8*)&slab[sbase[t] + koff];
                    acc[t] = __builtin_amdgcn_mfma_f32_32x32x16_bf16(
                                 af[kc], cvt.b, acc[t], 0, 0, 0);
                }
            }
        }
    }

    float* ob = out + (long)b * COUT * D4_ + (long)d0 * D3_ + (long)d1 * D2_;
    #pragma unroll
    for (int t = 0; t < 3; ++t) {
        #pragma unroll
        for (int r = 0; r < 16; ++r) {
            const int co = (r & 3) + 8 * (r >> 2) + 4 * hi;
            ob[(long)co * D4_ + ppos[t]] = acc[t][r];
        }
    }
}

extern "C" void kernel_launch(void* const* d_in, const int* in_sizes, int n_in,
                              void* d_out, int out_size, void* d_ws, size_t ws_size,
                              hipStream_t stream)
{
    const float* x = (const float*)d_in[0];
    const float* W = (const float*)d_in[1];
    float* out     = (float*)d_out;

    if (ws_size >= (size_t)WS_NEED) {
        hipFuncSetAttribute((const void*)conv4d_fused,
                            hipFuncAttributeMaxDynamicSharedMemorySize,
                            LDS_BYTES);
        hipMemsetAsync((char*)d_ws + CNT_OFF_B, 0, 64, stream);
        hipLaunchKernelGGL(conv4d_fused, dim3(GRID), dim3(NTHR), LDS_BYTES,
                           stream, x, W, out, (ushort_t*)d_ws);
    } else {
        hipLaunchKernelGGL(conv4d_mfma_fb, dim3(D * D, 2), dim3(384), 0, stream,
                           x, W, out);
    }
}

// Round 11
// 212.546 us; speedup vs baseline: 1.2252x; 1.2252x over previous
//
#include <hip/hip_runtime.h>

// 4D conv (K=3^4, SAME P=1), bf16 MFMA implicit GEMM, ONE fused kernel.
//  phase 1: x -> xt[b][d0(24)][p1(26)][h(2)][p2p3(676)][8ci] bf16 (k1/k2/k3 pad
//           baked in), W -> Wt[81][co][ci] bf16  (both in d_ws)
//  grid barrier (proven structure, 512 blocks all-resident)
//  phase 2: 512 blocks x 6 waves, 2 blocks/CU (TLP hides stalls - R8..R10 ran
//           1 block/CU lockstep). Per tile (b,d0,d1): nb = 3*(valid k0) bodies;
//           per body stage ONE 21.6 KB row (4 global_load_lds/wave) into
//           alternating LDS buffer. af single-buffered 9 frags (36 VGPR - the
//           108-VGPR triple buffer of R8..R10 spilled: WRITE_SIZE 145 vs 112 MB).
//           Issue order af(9) then stage(4) => auto af-wait is vmcnt(4), the
//           in-flight stage is never drained; body-top wait vmcnt(0)+s_barrier
//           (stage had a full body of MFMA cover).

#define D      24
#define D2_    (24*24)
#define D3_    (24*24*24)
#define D4_    (24*24*24*24)
#define CIN    16
#define COUT   32
#define TPW    3
#define NTHR   384          // 6 waves
#define GRID   512          // 2 blocks/CU resident -> grid barrier safe
#define NTILES (2*24*24)

#define ROW_USH   (2*676*8)       // 10816 ushorts = 21632 B per (b,d0,p1) row

#define XT_ELEMS  (2*24*26*26*26*16)
#define XT_BYTES  (XT_ELEMS*2)
#define WT_ELEMS  (81*32*16)
#define CNT_OFF_B (XT_BYTES + WT_ELEMS*2)
#define WS_NEED   (CNT_OFF_B + 64)

typedef __bf16 bf16x8 __attribute__((ext_vector_type(8)));
typedef float  f32x16 __attribute__((ext_vector_type(16)));
typedef unsigned short ushort_t;
typedef ushort_t ushort8 __attribute__((ext_vector_type(8)));
typedef ushort_t ushort4_ __attribute__((ext_vector_type(4)));

union u2b8 { ushort8 u; bf16x8 b; };

typedef const __attribute__((address_space(1))) unsigned int gu32;
typedef __attribute__((address_space(3))) unsigned int lu32;

__device__ inline ushort_t f2bf(float f) {
    union { float f; unsigned u; } x; x.f = f;
    unsigned r = x.u + 0x7FFFu + ((x.u >> 16) & 1u);   // RNE
    return (ushort_t)(r >> 16);
}

__global__ void __launch_bounds__(NTHR, 3) conv4d_fused(
    const float* __restrict__ x,
    const float* __restrict__ W,
    float* __restrict__ out,
    ushort_t* __restrict__ ws)
{
    __shared__ __align__(16) ushort_t slab[2][ROW_USH];   // 43264 B static

    ushort_t* xt = ws;
    ushort_t* Wt = ws + XT_BYTES / 2;
    unsigned* cnt = (unsigned*)((char*)ws + CNT_OFF_B);

    const int bk  = blockIdx.x;
    const int tid = threadIdx.x;

    // ---------------- phase 1: transpose/convert ----------------
    {
        const long gtid = (long)bk * NTHR + tid;
        const long nthr = (long)GRID * NTHR;
        for (long u = gtid; u < XT_ELEMS / 8; u += nthr) {
            const int pp = (int)(u % 676);
            long t2 = u / 676;
            const int h  = (int)(t2 & 1); t2 >>= 1;
            const int p1 = (int)(t2 % 26); t2 /= 26;
            const int d0 = (int)(t2 % 24);
            const int b  = (int)(t2 / 24);
            const int p2 = pp / 26, p3 = pp - 26 * (pp / 26);
            const int r1 = p1 - 1, r2 = p2 - 1, r3 = p3 - 1;
            ushort8 v;
            if ((unsigned)r1 < 24u && (unsigned)r2 < 24u && (unsigned)r3 < 24u) {
                const float* xp = x + (long)(b * 16 + h * 8) * D4_
                                    + d0 * D3_ + r1 * D2_ + r2 * D + r3;
                #pragma unroll
                for (int c = 0; c < 8; ++c) v[c] = f2bf(xp[(long)c * D4_]);
            } else {
                #pragma unroll
                for (int c = 0; c < 8; ++c) v[c] = 0;
            }
            *(ushort8*)&xt[u * 8] = v;
        }
        for (long i = gtid; i < WT_ELEMS; i += nthr) {
            const int tap = (int)(i >> 9);
            const int co  = (int)((i >> 4) & 31);
            const int ci  = (int)(i & 15);
            Wt[i] = f2bf(W[((long)co * 16 + ci) * 81 + tap]);
        }
    }

    // ---------------- grid barrier (proven structure) ----------------
    __threadfence();
    __syncthreads();
    if (tid == 0) {
        __hip_atomic_fetch_add(cnt, 1u, __ATOMIC_ACQ_REL, __HIP_MEMORY_SCOPE_AGENT);
        while (__hip_atomic_load(cnt, __ATOMIC_ACQUIRE, __HIP_MEMORY_SCOPE_AGENT)
               < (unsigned)GRID)
            __builtin_amdgcn_s_sleep(2);
    }
    __syncthreads();

    // ---------------- phase 2: pipelined implicit GEMM ----------------
    const int lane = tid & 63;
    const int wave = tid >> 6;          // 0..5
    const int col  = lane & 31;
    const int hi   = lane >> 5;

    int ppos[TPW], sbase[TPW];
    #pragma unroll
    for (int t = 0; t < TPW; ++t) {
        const int pos = (wave * TPW + t) * 32 + col;
        ppos[t]  = pos;
        sbase[t] = (hi * 676 + (pos / D) * 26 + (pos % D)) * 8;
    }

    for (int tile = bk; tile < NTILES; tile += GRID) {
        const int b   = tile / 576;
        const int d01 = tile % 576;
        const int d0  = d01 / 24;
        const int d1  = d01 % 24;

        const int k0lo = (d0 == 0) ? 1 : 0;
        const int k0hi = (d0 == 23) ? 1 : 2;
        const int nb   = (k0hi - k0lo + 1) * 3;   // 6 or 9 bodies

        f32x16 acc[TPW];
        #pragma unroll
        for (int t = 0; t < TPW; ++t)
            #pragma unroll
            for (int r = 0; r < 16; ++r) acc[t][r] = 0.f;

        // stage body i -> slab[i&1]: contiguous 21632 B (21 x 1KB + 128B tail)
        auto stage = [&](int i) {
            const int k0 = k0lo + i / 3, k1 = i - 3 * (i / 3);
            const int r0 = d0 + k0 - 1;                 // 0..23 by construction
            const ushort_t* src = xt + ((long)(b * 24 + r0) * 26 + (d1 + k1))
                                       * (long)ROW_USH;
            ushort_t* dst = &slab[i & 1][0];
            #pragma unroll
            for (int j = 0; j < 4; ++j) {
                const int c = wave + 6 * j;
                if (c < 22) {
                    const bool act = (c < 21) | (lane < 8);   // tail 128 B
                    if (act)
                        __builtin_amdgcn_global_load_lds(
                            (gu32*)src + (c * 256 + lane * 4),
                            (lu32*)(dst + c * 512), 16, 0, 0);
                }
            }
        };

        stage(0);
        for (int i = 0; i < nb; ++i) {
            // my stage(i) loads were the LAST vmem issued -> vmcnt(0) waits
            // exactly for them (full body of MFMA cover since issue).
            asm volatile("s_waitcnt vmcnt(0)" ::: "memory");
            asm volatile("s_barrier" ::: "memory");

            const ushort_t* sbuf = &slab[i & 1][0];
            const int k0 = k0lo + i / 3, k1 = i - 3 * (i / 3);

            // af (9 x dwordx4, 36 VGPR) BEFORE stage(i+1): auto af-wait is
            // vmcnt(4) -> never drains the in-flight stage (in-order vmcnt).
            bf16x8 af[9];
            {
                const ushort_t* w = Wt + (long)(k0 * 27 + k1 * 9) * 512
                                       + col * 16 + hi * 8;
                #pragma unroll
                for (int kc = 0; kc < 9; ++kc) {
                    u2b8 cvt; cvt.u = *(const ushort8*)(w + kc * 512);
                    af[kc] = cvt.b;
                }
            }
            asm volatile("" ::: "memory");   // pin: af issued before stage
            if (i + 1 < nb) stage(i + 1);
            asm volatile("" ::: "memory");   // pin: ds_reads/MFMA after stage

            __builtin_amdgcn_s_setprio(1);
            #pragma unroll
            for (int kc = 0; kc < 9; ++kc) {
                const int ko = ((kc / 3) * 26 + (kc % 3)) * 8;   // imm
                #pragma unroll
                for (int t = 0; t < TPW; ++t) {
                    u2b8 cvt;
                    cvt.u = *(const ushort8*)&sbuf[sbase[t] + ko];
                    acc[t] = __builtin_amdgcn_mfma_f32_32x32x16_bf16(
                                 af[kc], cvt.b, acc[t], 0, 0, 0);
                }
            }
            __builtin_amdgcn_s_setprio(0);
        }

        // epilogue: row=co=(r&3)+8*(r>>2)+4*hi, col=pos
        float* ob = out + (long)b * COUT * D4_ + (long)d0 * D3_ + (long)d1 * D2_;
        #pragma unroll
        for (int t = 0; t < TPW; ++t) {
            #pragma unroll
            for (int r = 0; r < 16; ++r) {
                const int co = (r & 3) + 8 * (r >> 2) + 4 * hi;
                ob[(long)co * D4_ + ppos[t]] = acc[t][r];
            }
        }
        // all waves done reading slab before next tile's stage(0) overwrites
        asm volatile("s_barrier" ::: "memory");
    }
}

// ===================== fallback (proven R4 kernel) =====================
__device__ inline int fswz(int f) { return f ^ ((f >> 3) & 7); }

__global__ __launch_bounds__(384) void conv4d_mfma_fb(
    const float* __restrict__ x,
    const float* __restrict__ W,
    float* __restrict__ out)
{
    __shared__ __align__(16) ushort_t slab[26 * 26 * CIN];
    __shared__ __align__(16) ushort_t agrp[9 * COUT * CIN];

    const int d01  = blockIdx.x;
    const int b    = blockIdx.y;
    const int d0   = d01 / D;
    const int d1   = d01 % D;
    const int tid  = threadIdx.x;
    const int lane = tid & 63;
    const int wave = tid >> 6;
    const int col  = lane & 31;
    const int hi   = lane >> 5;

    const int afbase = fswz(col * 2 + hi) * 8;
    int ppos[3], sbase[3];
    #pragma unroll
    for (int t = 0; t < 3; ++t) {
        int pos = (wave * 3 + t) * 32 + col;
        ppos[t]  = pos;
        sbase[t] = ((pos / D) * 26 + (pos % D)) * CIN + hi * 8;
    }

    f32x16 acc[3];
    #pragma unroll
    for (int t = 0; t < 3; ++t)
        #pragma unroll
        for (int r = 0; r < 16; ++r) acc[t][r] = 0.f;

    const float* xb = x + (long)b * CIN * D4_;

    for (int k0 = 0; k0 < 3; ++k0) {
        const int r0 = d0 + k0 - 1;
        if ((unsigned)r0 >= (unsigned)D) continue;
        for (int k1 = 0; k1 < 3; ++k1) {
            const int r1 = d1 + k1 - 1;
            if ((unsigned)r1 >= (unsigned)D) continue;

            __syncthreads();

            const float* xp = xb + (long)r0 * D3_ + (long)r1 * D2_;
            for (int idx = tid; idx < 26 * 26 * 2; idx += 384) {
                const int pidx = idx >> 1;
                const int h    = idx & 1;
                const int p2   = pidx / 26;
                const int p3   = pidx - p2 * 26;
                const int s2   = p2 - 1;
                const int s3   = p3 - 1;
                const bool in  = (unsigned)s2 < (unsigned)D &&
                                 (unsigned)s3 < (unsigned)D;
                const float* xs = xp + s2 * D + s3;
                ushort8 v;
                #pragma unroll
                for (int c = 0; c < 8; ++c) {
                    float f = in ? xs[(long)(h * 8 + c) * D4_] : 0.f;
                    v[c] = f2bf(f);
                }
                *(ushort8*)&slab[idx * 8] = v;
            }

            const int kw0 = k0 * 27 + k1 * 9;
            for (int u = tid; u < 9 * COUT * 4; u += 384) {
                const int tap = u >> 7;
                const int rem = u & 127;
                const int co  = rem >> 2;
                const int q   = rem & 3;
                const int ci0 = (q >> 1) * 8 + (q & 1) * 4;
                const float* wp = W + co * (CIN * 81) + kw0 + tap;
                ushort4_ v;
                #pragma unroll
                for (int c = 0; c < 4; ++c)
                    v[c] = f2bf(wp[(ci0 + c) * 81]);
                const int f  = co * 2 + (q >> 1);
                const int h2 = q & 1;
                *(ushort4_*)&agrp[tap * 512 + fswz(f) * 8 + h2 * 4] = v;
            }
            __syncthreads();

            bf16x8 af[9];
            #pragma unroll
            for (int kc = 0; kc < 9; ++kc) {
                u2b8 cvt;
                cvt.u = *(const ushort8*)&agrp[kc * 512 + afbase];
                af[kc] = cvt.b;
            }

            #pragma unroll
            for (int kc = 0; kc < 9; ++kc) {
                const int koff = ((kc / 3) * 26 + (kc % 3)) * CIN;
                #pragma unroll
                for (int t = 0; t < 3; ++t) {
                    u2b8 cvt;
                    cvt.u = *(const ushort8*)&slab[sbase[t] + koff];
                    acc[t] = __builtin_amdgcn_mfma_f32_32x32x16_bf16(
                                 af[kc], cvt.b, acc[t], 0, 0, 0);
                }
            }
        }
    }

    float* ob = out + (long)b * COUT * D4_ + (long)d0 * D3_ + (long)d1 * D2_;
    #pragma unroll
    for (int t = 0; t < 3; ++t) {
        #pragma unroll
        for (int r = 0; r < 16; ++r) {
            const int co = (r & 3) + 8 * (r >> 2) + 4 * hi;
            ob[(long)co * D4_ + ppos[t]] = acc[t][r];
        }
    }
}

extern "C" void kernel_launch(void* const* d_in, const int* in_sizes, int n_in,
                              void* d_out, int out_size, void* d_ws, size_t ws_size,
                              hipStream_t stream)
{
    const float* x = (const float*)d_in[0];
    const float* W = (const float*)d_in[1];
    float* out     = (float*)d_out;

    if (ws_size >= (size_t)WS_NEED) {
        hipMemsetAsync((char*)d_ws + CNT_OFF_B, 0, 64, stream);
        hipLaunchKernelGGL(conv4d_fused, dim3(GRID), dim3(NTHR), 0, stream,
                           x, W, out, (ushort_t*)d_ws);
    } else {
        hipLaunchKernelGGL(conv4d_mfma_fb, dim3(D * D, 2), dim3(384), 0, stream,
                           x, W, out);
    }
}

// Round 17
// 208.743 us; speedup vs baseline: 1.2475x; 1.0182x over previous
//
#include <hip/hip_runtime.h>

// 4D conv (K=3^4, SAME P=1), bf16 MFMA implicit GEMM, ONE fused kernel.
// == The proven R5 kernel (177.9 us, passed) with ONE delta: GRID 256->512 +
// launch_bounds(384,3) => 2 blocks/CU resident. R5 ran 1 block/CU in barrier
// lockstep (Occupancy 16%); every __syncthreads() drained vmcnt and exposed
// stage latency. A second anti-phased block per CU covers those stalls (TLP).
// No new sync semantics (the R12/R16 raw-barrier+vmcnt(9) structure timed out
// twice on HW -- abandoned).
//  phase 1: x -> xt[b][d0(24)][p1(26)][h(2)][p2p3(676)][8ci] bf16 (pad baked in)
//           W -> Wt[81][co][ci] bf16   (both in d_ws)
//  grid barrier (proven), then per tile (b,d0,d1): nb bodies; per body:
//  __syncthreads -> stage(i+1) via global_load_lds -> af[9] loads -> 27 MFMA.

#define D      24
#define D2_    (24*24)
#define D3_    (24*24*24)
#define D4_    (24*24*24*24)
#define CIN    16
#define COUT   32
#define TPW    3
#define NTHR   384          // 6 waves
#define GRID   512          // 2 blocks/CU resident (LDS 43KB->3/CU, VGPR cap 168)
#define NTILES (2*24*24)

#define ROW_USH   (2*676*8)       // 10816 ushorts = 21632 B per (b,d0,p1) row

#define XT_ELEMS  (2*24*26*26*26*16)
#define XT_BYTES  (XT_ELEMS*2)
#define WT_ELEMS  (81*32*16)
#define CNT_OFF_B (XT_BYTES + WT_ELEMS*2)
#define WS_NEED   (CNT_OFF_B + 64)

typedef __bf16 bf16x8 __attribute__((ext_vector_type(8)));
typedef float  f32x16 __attribute__((ext_vector_type(16)));
typedef unsigned short ushort_t;
typedef ushort_t ushort8 __attribute__((ext_vector_type(8)));
typedef ushort_t ushort4_ __attribute__((ext_vector_type(4)));

union u2b8 { ushort8 u; bf16x8 b; };

typedef const __attribute__((address_space(1))) unsigned int gu32;
typedef __attribute__((address_space(3))) unsigned int lu32;

__device__ inline ushort_t f2bf(float f) {
    union { float f; unsigned u; } x; x.f = f;
    unsigned r = x.u + 0x7FFFu + ((x.u >> 16) & 1u);   // RNE
    return (ushort_t)(r >> 16);
}

__global__ void __launch_bounds__(NTHR, 3) conv4d_fused(
    const float* __restrict__ x,
    const float* __restrict__ W,
    float* __restrict__ out,
    ushort_t* __restrict__ ws)
{
    __shared__ __align__(16) ushort_t slab[2][ROW_USH];   // 43264 B

    ushort_t* xt = ws;
    ushort_t* Wt = ws + XT_BYTES / 2;
    unsigned* cnt = (unsigned*)((char*)ws + CNT_OFF_B);

    const int bk  = blockIdx.x;
    const int tid = threadIdx.x;

    // ---------------- phase 1: transpose/convert ----------------
    {
        const long gtid = (long)bk * NTHR + tid;
        const long nthr = (long)GRID * NTHR;
        for (long u = gtid; u < XT_ELEMS / 8; u += nthr) {
            const int pp = (int)(u % 676);
            long t2 = u / 676;
            const int h  = (int)(t2 & 1); t2 >>= 1;
            const int p1 = (int)(t2 % 26); t2 /= 26;
            const int d0 = (int)(t2 % 24);
            const int b  = (int)(t2 / 24);
            const int p2 = pp / 26, p3 = pp - 26 * (pp / 26);
            const int r1 = p1 - 1, r2 = p2 - 1, r3 = p3 - 1;
            ushort8 v;
            if ((unsigned)r1 < 24u && (unsigned)r2 < 24u && (unsigned)r3 < 24u) {
                const float* xp = x + (long)(b * 16 + h * 8) * D4_
                                    + d0 * D3_ + r1 * D2_ + r2 * D + r3;
                #pragma unroll
                for (int c = 0; c < 8; ++c) v[c] = f2bf(xp[(long)c * D4_]);
            } else {
                #pragma unroll
                for (int c = 0; c < 8; ++c) v[c] = 0;
            }
            *(ushort8*)&xt[u * 8] = v;
        }
        for (long i = gtid; i < WT_ELEMS; i += nthr) {
            const int tap = (int)(i >> 9);
            const int co  = (int)((i >> 4) & 31);
            const int ci  = (int)(i & 15);
            Wt[i] = f2bf(W[((long)co * 16 + ci) * 81 + tap]);
        }
    }

    // ---------------- grid barrier (proven structure) ----------------
    __threadfence();
    __syncthreads();
    if (tid == 0) {
        __hip_atomic_fetch_add(cnt, 1u, __ATOMIC_ACQ_REL, __HIP_MEMORY_SCOPE_AGENT);
        while (__hip_atomic_load(cnt, __ATOMIC_ACQUIRE, __HIP_MEMORY_SCOPE_AGENT)
               < (unsigned)GRID)
            __builtin_amdgcn_s_sleep(2);
    }
    __syncthreads();

    // ---------------- phase 2: implicit GEMM ----------------
    const int lane = tid & 63;
    const int wave = tid >> 6;          // 0..5
    const int col  = lane & 31;
    const int hi   = lane >> 5;

    int ppos[TPW], sbase[TPW];
    #pragma unroll
    for (int t = 0; t < TPW; ++t) {
        const int pos = (wave * TPW + t) * 32 + col;
        ppos[t]  = pos;
        sbase[t] = (hi * 676 + (pos / D) * 26 + (pos % D)) * 8;
    }

    for (int tile = bk; tile < NTILES; tile += GRID) {
        const int b   = tile / 576;
        const int d01 = tile % 576;
        const int d0  = d01 / 24;
        const int d1  = d01 % 24;

        const int k0lo = (d0 == 0) ? 1 : 0;
        const int k0hi = (d0 == 23) ? 1 : 2;
        const int nb   = (k0hi - k0lo + 1) * 3;   // 6 or 9 bodies

        f32x16 acc[TPW];
        #pragma unroll
        for (int t = 0; t < TPW; ++t)
            #pragma unroll
            for (int r = 0; r < 16; ++r) acc[t][r] = 0.f;

        // stage body i -> slab[i&1]: 21632 B (21 x 1KB + 128B tail).
        // c = wave + 6j, j=0..3; c<22; c==21 tail lanes<8.
        auto stage = [&](int i) {
            const int k0 = k0lo + i / 3, k1 = i - 3 * (i / 3);
            const int r0 = d0 + k0 - 1;                 // 0..23 by construction
            const ushort_t* src = xt + ((long)(b * 24 + r0) * 26 + (d1 + k1))
                                       * (long)ROW_USH;
            ushort_t* dst = &slab[i & 1][0];
            #pragma unroll
            for (int j = 0; j < 4; ++j) {
                const int c = wave + 6 * j;
                if (c < 22) {
                    const bool act = (c < 21) | (lane < 8);   // tail 128 B
                    if (act)
                        __builtin_amdgcn_global_load_lds(
                            (gu32*)src + (c * 256 + lane * 4),
                            (lu32*)(dst + c * 512), 16, 0, 0);
                }
            }
        };

        stage(0);
        for (int i = 0; i < nb; ++i) {
            __syncthreads();   // slab[i&1] landed (drains vmcnt); prev compute done

            if (i + 1 < nb) stage(i + 1);

            const ushort_t* sbuf = &slab[i & 1][0];
            const int k0 = k0lo + i / 3, k1 = i - 3 * (i / 3);

            bf16x8 af[9];
            {
                const ushort_t* w = Wt + (long)(k0 * 27 + k1 * 9) * 512
                                       + col * 16 + hi * 8;
                #pragma unroll
                for (int kc = 0; kc < 9; ++kc) {
                    u2b8 cvt; cvt.u = *(const ushort8*)(w + kc * 512);
                    af[kc] = cvt.b;
                }
            }

            __builtin_amdgcn_s_setprio(1);
            #pragma unroll
            for (int kc = 0; kc < 9; ++kc) {
                const int ko = ((kc / 3) * 26 + (kc % 3)) * 8;   // imm
                #pragma unroll
                for (int t = 0; t < TPW; ++t) {
                    u2b8 cvt;
                    cvt.u = *(const ushort8*)&sbuf[sbase[t] + ko];
                    acc[t] = __builtin_amdgcn_mfma_f32_32x32x16_bf16(
                                 af[kc], cvt.b, acc[t], 0, 0, 0);
                }
            }
            __builtin_amdgcn_s_setprio(0);
        }

        // epilogue: row=co=(r&3)+8*(r>>2)+4*hi, col=pos
        float* ob = out + (long)b * COUT * D4_ + (long)d0 * D3_ + (long)d1 * D2_;
        #pragma unroll
        for (int t = 0; t < TPW; ++t) {
            #pragma unroll
            for (int r = 0; r < 16; ++r) {
                const int co = (r & 3) + 8 * (r >> 2) + 4 * hi;
                ob[(long)co * D4_ + ppos[t]] = acc[t][r];
            }
        }
        __syncthreads();   // all waves done reading slab before next tile
    }
}

// ===================== fallback (proven R4 kernel) =====================
__device__ inline int fswz(int f) { return f ^ ((f >> 3) & 7); }

__global__ __launch_bounds__(384) void conv4d_mfma_fb(
    const float* __restrict__ x,
    const float* __restrict__ W,
    float* __restrict__ out)
{
    __shared__ __align__(16) ushort_t slab[26 * 26 * CIN];
    __shared__ __align__(16) ushort_t agrp[9 * COUT * CIN];

    const int d01  = blockIdx.x;
    const int b    = blockIdx.y;
    const int d0   = d01 / D;
    const int d1   = d01 % D;
    const int tid  = threadIdx.x;
    const int lane = tid & 63;
    const int wave = tid >> 6;
    const int col  = lane & 31;
    const int hi   = lane >> 5;

    const int afbase = fswz(col * 2 + hi) * 8;
    int ppos[3], sbase[3];
    #pragma unroll
    for (int t = 0; t < 3; ++t) {
        int pos = (wave * 3 + t) * 32 + col;
        ppos[t]  = pos;
        sbase[t] = ((pos / D) * 26 + (pos % D)) * CIN + hi * 8;
    }

    f32x16 acc[3];
    #pragma unroll
    for (int t = 0; t < 3; ++t)
        #pragma unroll
        for (int r = 0; r < 16; ++r) acc[t][r] = 0.f;

    const float* xb = x + (long)b * CIN * D4_;

    for (int k0 = 0; k0 < 3; ++k0) {
        const int r0 = d0 + k0 - 1;
        if ((unsigned)r0 >= (unsigned)D) continue;
        for (int k1 = 0; k1 < 3; ++k1) {
            const int r1 = d1 + k1 - 1;
            if ((unsigned)r1 >= (unsigned)D) continue;

            __syncthreads();

            const float* xp = xb + (long)r0 * D3_ + (long)r1 * D2_;
            for (int idx = tid; idx < 26 * 26 * 2; idx += 384) {
                const int pidx = idx >> 1;
                const int h    = idx & 1;
                const int p2   = pidx / 26;
                const int p3   = pidx - p2 * 26;
                const int s2   = p2 - 1;
                const int s3   = p3 - 1;
                const bool in  = (unsigned)s2 < (unsigned)D &&
                                 (unsigned)s3 < (unsigned)D;
                const float* xs = xp + s2 * D + s3;
                ushort8 v;
                #pragma unroll
                for (int c = 0; c < 8; ++c) {
                    float f = in ? xs[(long)(h * 8 + c) * D4_] : 0.f;
                    v[c] = f2bf(f);
                }
                *(ushort8*)&slab[idx * 8] = v;
            }

            const int kw0 = k0 * 27 + k1 * 9;
            for (int u = tid; u < 9 * COUT * 4; u += 384) {
                const int tap = u >> 7;
                const int rem = u & 127;
                const int co  = rem >> 2;
                const int q   = rem & 3;
                const int ci0 = (q >> 1) * 8 + (q & 1) * 4;
                const float* wp = W + co * (CIN * 81) + kw0 + tap;
                ushort4_ v;
                #pragma unroll
                for (int c = 0; c < 4; ++c)
                    v[c] = f2bf(wp[(ci0 + c) * 81]);
                const int f  = co * 2 + (q >> 1);
                const int h2 = q & 1;
                *(ushort4_*)&agrp[tap * 512 + fswz(f) * 8 + h2 * 4] = v;
            }
            __syncthreads();

            bf16x8 af[9];
            #pragma unroll
            for (int kc = 0; kc < 9; ++kc) {
                u2b8 cvt;
                cvt.u = *(const ushort8*)&agrp[kc * 512 + afbase];
                af[kc] = cvt.b;
            }

            #pragma unroll
            for (int kc = 0; kc < 9; ++kc) {
                const int koff = ((kc / 3) * 26 + (kc % 3)) * CIN;
                #pragma unroll
                for (int t = 0; t < 3; ++t) {
                    u2b8 cvt;
                    cvt.u = *(const ushort8*)&slab[sbase[t] + koff];
                    acc[t] = __builtin_amdgcn_mfma_f32_32x32x16_bf16(
                                 af[kc], cvt.b, acc[t], 0, 0, 0);
                }
            }
        }
    }

    float* ob = out + (long)b * COUT * D4_ + (long)d0 * D3_ + (long)d1 * D2_;
    #pragma unroll
    for (int t = 0; t < 3; ++t) {
        #pragma unroll
        for (int r = 0; r < 16; ++r) {
            const int co = (r & 3) + 8 * (r >> 2) + 4 * hi;
            ob[(long)co * D4_ + ppos[t]] = acc[t][r];
        }
    }
}

extern "C" void kernel_launch(void* const* d_in, const int* in_sizes, int n_in,
                              void* d_out, int out_size, void* d_ws, size_t ws_size,
                              hipStream_t stream)
{
    const float* x = (const float*)d_in[0];
    const float* W = (const float*)d_in[1];
    float* out     = (float*)d_out;

    if (ws_size >= (size_t)WS_NEED) {
        hipMemsetAsync((char*)d_ws + CNT_OFF_B, 0, 64, stream);
        hipLaunchKernelGGL(conv4d_fused, dim3(GRID), dim3(NTHR), 0, stream,
                           x, W, out, (ushort_t*)d_ws);
    } else {
        hipLaunchKernelGGL(conv4d_mfma_fb, dim3(D * D, 2), dim3(384), 0, stream,
                           x, W, out);
    }
}

// Round 19
// 158.073 us; speedup vs baseline: 1.6474x; 1.3206x over previous
//
#include <hip/hip_runtime.h>

// 4D conv (K=3^4, SAME P=1), bf16 MFMA implicit GEMM, ONE fused kernel.
// Base = R5 champion (177.9 us, GRID=256, NTHR=384, 2-slab syncthreads loop).
// KEY DELTA: weights live in LDS (staged once per block, 82.9 KB, fswz layout
// proven in R4) => per-body af reads are ds_read_b128 (lgkmcnt), NOT global
// loads (vmcnt). This removes the transitive-vmcnt serialization: in R5 the
// compute's wait for the 9 youngest af vmem ops forced stage(i+1) to complete
// every body. Now the body has zero vmem waits; stage(i+1) flies until the
// next __syncthreads (a full body of cover).
// NO af cross-body double-buffer (3/3 GPU hangs: R12/R16/R18), no raw
// barriers, no counted vmcnt — plain __syncthreads semantics only.
// LDS: 82944 (W) + 2x21632 (slabs) = 126208 B dynamic (R8-proven attribute),
// 1 block/CU, GRID=256 all-resident -> grid barrier safe.

#define D      24
#define D2_    (24*24)
#define D3_    (24*24*24)
#define D4_    (24*24*24*24)
#define CIN    16
#define COUT   32
#define TPW    3
#define NTHR   384          // 6 waves
#define GRID   256          // 1 block/CU (126KB LDS) -> all resident
#define NTILES (2*24*24)

#define ROW_USH   (2*676*8)       // 10816 ushorts = 21632 B per (b,d0,p1) row
#define WL_USH    (81*512)        // 41472 ushorts = 82944 B weights in LDS
#define LDS_BYTES ((WL_USH + 2*ROW_USH) * 2)   // 126208 B

#define XT_ELEMS  (2*24*26*26*26*16)
#define XT_BYTES  (XT_ELEMS*2)
#define WT_ELEMS  (81*32*16)
#define CNT_OFF_B (XT_BYTES + WT_ELEMS*2)
#define WS_NEED   (CNT_OFF_B + 64)

typedef __bf16 bf16x8 __attribute__((ext_vector_type(8)));
typedef float  f32x16 __attribute__((ext_vector_type(16)));
typedef unsigned short ushort_t;
typedef ushort_t ushort8 __attribute__((ext_vector_type(8)));
typedef ushort_t ushort4_ __attribute__((ext_vector_type(4)));

union u2b8 { ushort8 u; bf16x8 b; };

typedef const __attribute__((address_space(1))) unsigned int gu32;
typedef __attribute__((address_space(3))) unsigned int lu32;

__device__ inline ushort_t f2bf(float f) {
    union { float f; unsigned u; } x; x.f = f;
    unsigned r = x.u + 0x7FFFu + ((x.u >> 16) & 1u);   // RNE
    return (ushort_t)(r >> 16);
}

// fragment swizzle (R4-proven): spreads stride-32B b128 reads across banks
__device__ inline int fswz(int f) { return f ^ ((f >> 3) & 7); }

__global__ void __launch_bounds__(NTHR) conv4d_fused(
    const float* __restrict__ x,
    const float* __restrict__ W,
    float* __restrict__ out,
    ushort_t* __restrict__ ws)
{
    extern __shared__ __align__(16) ushort_t lds[];
    ushort_t* ldsW  = lds;                       // 41472 ushorts (82944 B)
    ushort_t* slabs = lds + WL_USH;              // 2 x 10816 ushorts

    ushort_t* xt = ws;
    ushort_t* Wt = ws + XT_BYTES / 2;            // fswz'd [81][frag][8] layout
    unsigned* cnt = (unsigned*)((char*)ws + CNT_OFF_B);

    const int bk  = blockIdx.x;
    const int tid = threadIdx.x;

    // ---------------- phase 1: transpose/convert ----------------
    {
        const long gtid = (long)bk * NTHR + tid;
        const long nthr = (long)GRID * NTHR;
        for (long u = gtid; u < XT_ELEMS / 8; u += nthr) {
            const int pp = (int)(u % 676);
            long t2 = u / 676;
            const int h  = (int)(t2 & 1); t2 >>= 1;
            const int p1 = (int)(t2 % 26); t2 /= 26;
            const int d0 = (int)(t2 % 24);
            const int b  = (int)(t2 / 24);
            const int p2 = pp / 26, p3 = pp - 26 * (pp / 26);
            const int r1 = p1 - 1, r2 = p2 - 1, r3 = p3 - 1;
            ushort8 v;
            if ((unsigned)r1 < 24u && (unsigned)r2 < 24u && (unsigned)r3 < 24u) {
                const float* xp = x + (long)(b * 16 + h * 8) * D4_
                                    + d0 * D3_ + r1 * D2_ + r2 * D + r3;
                #pragma unroll
                for (int c = 0; c < 8; ++c) v[c] = f2bf(xp[(long)c * D4_]);
            } else {
                #pragma unroll
                for (int c = 0; c < 8; ++c) v[c] = 0;
            }
            *(ushort8*)&xt[u * 8] = v;
        }
        // W -> Wt with fswz layout baked in (so the LDS copy is LINEAR):
        // dst = tap*512 + fswz(co*2 + (ci>>3))*8 + (ci&7)
        for (long i = gtid; i < WT_ELEMS; i += nthr) {
            const int tap = (int)(i >> 9);
            const int co  = (int)((i >> 4) & 31);
            const int ci  = (int)(i & 15);
            const int f   = fswz(co * 2 + (ci >> 3));
            Wt[tap * 512 + f * 8 + (ci & 7)] =
                f2bf(W[((long)co * 16 + ci) * 81 + tap]);
        }
    }

    // ---------------- grid barrier (proven structure) ----------------
    __threadfence();
    __syncthreads();
    if (tid == 0) {
        __hip_atomic_fetch_add(cnt, 1u, __ATOMIC_ACQ_REL, __HIP_MEMORY_SCOPE_AGENT);
        while (__hip_atomic_load(cnt, __ATOMIC_ACQUIRE, __HIP_MEMORY_SCOPE_AGENT)
               < (unsigned)GRID)
            __builtin_amdgcn_s_sleep(2);
    }
    __syncthreads();

    // ---------------- phase 2: implicit GEMM ----------------
    const int lane = tid & 63;
    const int wave = tid >> 6;          // 0..5
    const int col  = lane & 31;
    const int hi   = lane >> 5;

    // stage full weight block 82944 B -> ldsW (81 x 1KB chunks, linear copy).
    // Drained by the first tile's body-0 __syncthreads.
    for (int c = wave; c < 81; c += 6)
        __builtin_amdgcn_global_load_lds(
            (gu32*)Wt + (c * 256 + lane * 4),
            (lu32*)(ldsW + c * 512), 16, 0, 0);

    const int afb = fswz(col * 2 + hi) * 8;   // ushort offset within tap slot

    int ppos[TPW], sbase[TPW];
    #pragma unroll
    for (int t = 0; t < TPW; ++t) {
        const int pos = (wave * TPW + t) * 32 + col;
        ppos[t]  = pos;
        sbase[t] = (hi * 676 + (pos / D) * 26 + (pos % D)) * 8;
    }

    for (int tile = bk; tile < NTILES; tile += GRID) {
        const int b   = tile / 576;
        const int d01 = tile % 576;
        const int d0  = d01 / 24;
        const int d1  = d01 % 24;

        const int k0lo = (d0 == 0) ? 1 : 0;
        const int k0hi = (d0 == 23) ? 1 : 2;
        const int nb   = (k0hi - k0lo + 1) * 3;   // 6 or 9 bodies

        f32x16 acc[TPW];
        #pragma unroll
        for (int t = 0; t < TPW; ++t)
            #pragma unroll
            for (int r = 0; r < 16; ++r) acc[t][r] = 0.f;

        // stage body i -> slab (i&1): 21632 B (21 x 1KB + 128B tail).
        auto stage = [&](int i) {
            const int k0 = k0lo + i / 3, k1 = i - 3 * (i / 3);
            const int r0 = d0 + k0 - 1;                 // 0..23 by construction
            const ushort_t* src = xt + ((long)(b * 24 + r0) * 26 + (d1 + k1))
                                       * (long)ROW_USH;
            ushort_t* dst = slabs + (i & 1) * ROW_USH;
            #pragma unroll
            for (int j = 0; j < 4; ++j) {
                const int c = wave + 6 * j;
                if (c < 22) {
                    const bool act = (c < 21) | (lane < 8);   // tail 128 B
                    if (act)
                        __builtin_amdgcn_global_load_lds(
                            (gu32*)src + (c * 256 + lane * 4),
                            (lu32*)(dst + c * 512), 16, 0, 0);
                }
            }
        };

        stage(0);
        for (int i = 0; i < nb; ++i) {
            __syncthreads();   // slab(i) AND (first time) ldsW landed

            if (i + 1 < nb) stage(i + 1);   // in flight for the whole body

            const ushort_t* sbuf = slabs + (i & 1) * ROW_USH;
            const int k0 = k0lo + i / 3, k1 = i - 3 * (i / 3);

            // af from LDS: 9 x ds_read_b128 (lgkmcnt) — NO vmem dependency,
            // so nothing in this body waits on stage(i+1).
            const ushort_t* wl = ldsW + (long)(k0 * 27 + k1 * 9) * 512 + afb;
            bf16x8 af[9];
            #pragma unroll
            for (int kc = 0; kc < 9; ++kc) {
                u2b8 cvt; cvt.u = *(const ushort8*)(wl + kc * 512);
                af[kc] = cvt.b;
            }

            __builtin_amdgcn_s_setprio(1);
            #pragma unroll
            for (int kc = 0; kc < 9; ++kc) {
                const int ko = ((kc / 3) * 26 + (kc % 3)) * 8;   // imm
                #pragma unroll
                for (int t = 0; t < TPW; ++t) {
                    u2b8 cvt;
                    cvt.u = *(const ushort8*)&sbuf[sbase[t] + ko];
                    acc[t] = __builtin_amdgcn_mfma_f32_32x32x16_bf16(
                                 af[kc], cvt.b, acc[t], 0, 0, 0);
                }
            }
            __builtin_amdgcn_s_setprio(0);
        }

        // epilogue: row=co=(r&3)+8*(r>>2)+4*hi, col=pos
        float* ob = out + (long)b * COUT * D4_ + (long)d0 * D3_ + (long)d1 * D2_;
        #pragma unroll
        for (int t = 0; t < TPW; ++t) {
            #pragma unroll
            for (int r = 0; r < 16; ++r) {
                const int co = (r & 3) + 8 * (r >> 2) + 4 * hi;
                ob[(long)co * D4_ + ppos[t]] = acc[t][r];
            }
        }
        __syncthreads();   // all waves done reading slab before next tile
    }
}

// ===================== fallback (proven R4 kernel) =====================
__global__ __launch_bounds__(384) void conv4d_mfma_fb(
    const float* __restrict__ x,
    const float* __restrict__ W,
    float* __restrict__ out)
{
    __shared__ __align__(16) ushort_t slab[26 * 26 * CIN];
    __shared__ __align__(16) ushort_t agrp[9 * COUT * CIN];

    const int d01  = blockIdx.x;
    const int b    = blockIdx.y;
    const int d0   = d01 / D;
    const int d1   = d01 % D;
    const int tid  = threadIdx.x;
    const int lane = tid & 63;
    const int wave = tid >> 6;
    const int col  = lane & 31;
    const int hi   = lane >> 5;

    const int afbase = fswz(col * 2 + hi) * 8;
    int ppos[3], sbase[3];
    #pragma unroll
    for (int t = 0; t < 3; ++t) {
        int pos = (wave * 3 + t) * 32 + col;
        ppos[t]  = pos;
        sbase[t] = ((pos / D) * 26 + (pos % D)) * CIN + hi * 8;
    }

    f32x16 acc[3];
    #pragma unroll
    for (int t = 0; t < 3; ++t)
        #pragma unroll
        for (int r = 0; r < 16; ++r) acc[t][r] = 0.f;

    const float* xb = x + (long)b * CIN * D4_;

    for (int k0 = 0; k0 < 3; ++k0) {
        const int r0 = d0 + k0 - 1;
        if ((unsigned)r0 >= (unsigned)D) continue;
        for (int k1 = 0; k1 < 3; ++k1) {
            const int r1 = d1 + k1 - 1;
            if ((unsigned)r1 >= (unsigned)D) continue;

            __syncthreads();

            const float* xp = xb + (long)r0 * D3_ + (long)r1 * D2_;
            for (int idx = tid; idx < 26 * 26 * 2; idx += 384) {
                const int pidx = idx >> 1;
                const int h    = idx & 1;
                const int p2   = pidx / 26;
                const int p3   = pidx - p2 * 26;
                const int s2   = p2 - 1;
                const int s3   = p3 - 1;
                const bool in  = (unsigned)s2 < (unsigned)D &&
                                 (unsigned)s3 < (unsigned)D;
                const float* xs = xp + s2 * D + s3;
                ushort8 v;
                #pragma unroll
                for (int c = 0; c < 8; ++c) {
                    float f = in ? xs[(long)(h * 8 + c) * D4_] : 0.f;
                    v[c] = f2bf(f);
                }
                *(ushort8*)&slab[idx * 8] = v;
            }

            const int kw0 = k0 * 27 + k1 * 9;
            for (int u = tid; u < 9 * COUT * 4; u += 384) {
                const int tap = u >> 7;
                const int rem = u & 127;
                const int co  = rem >> 2;
                const int q   = rem & 3;
                const int ci0 = (q >> 1) * 8 + (q & 1) * 4;
                const float* wp = W + co * (CIN * 81) + kw0 + tap;
                ushort4_ v;
                #pragma unroll
                for (int c = 0; c < 4; ++c)
                    v[c] = f2bf(wp[(ci0 + c) * 81]);
                const int f  = co * 2 + (q >> 1);
                const int h2 = q & 1;
                *(ushort4_*)&agrp[tap * 512 + fswz(f) * 8 + h2 * 4] = v;
            }
            __syncthreads();

            bf16x8 af[9];
            #pragma unroll
            for (int kc = 0; kc < 9; ++kc) {
                u2b8 cvt;
                cvt.u = *(const ushort8*)&agrp[kc * 512 + afbase];
                af[kc] = cvt.b;
            }

            #pragma unroll
            for (int kc = 0; kc < 9; ++kc) {
                const int koff = ((kc / 3) * 26 + (kc % 3)) * CIN;
                #pragma unroll
                for (int t = 0; t < 3; ++t) {
                    u2b8 cvt;
                    cvt.u = *(const ushort8*)&slab[sbase[t] + koff];
                    acc[t] = __builtin_amdgcn_mfma_f32_32x32x16_bf16(
                                 af[kc], cvt.b, acc[t], 0, 0, 0);
                }
            }
        }
    }

    float* ob = out + (long)b * COUT * D4_ + (long)d0 * D3_ + (long)d1 * D2_;
    #pragma unroll
    for (int t = 0; t < 3; ++t) {
        #pragma unroll
        for (int r = 0; r < 16; ++r) {
            const int co = (r & 3) + 8 * (r >> 2) + 4 * hi;
            ob[(long)co * D4_ + ppos[t]] = acc[t][r];
        }
    }
}

extern "C" void kernel_launch(void* const* d_in, const int* in_sizes, int n_in,
                              void* d_out, int out_size, void* d_ws, size_t ws_size,
                              hipStream_t stream)
{
    const float* x = (const float*)d_in[0];
    const float* W = (const float*)d_in[1];
    float* out     = (float*)d_out;

    if (ws_size >= (size_t)WS_NEED) {
        hipFuncSetAttribute((const void*)conv4d_fused,
                            hipFuncAttributeMaxDynamicSharedMemorySize,
                            LDS_BYTES);
        hipMemsetAsync((char*)d_ws + CNT_OFF_B, 0, 64, stream);
        hipLaunchKernelGGL(conv4d_fused, dim3(GRID), dim3(NTHR), LDS_BYTES,
                           stream, x, W, out, (ushort_t*)d_ws);
    } else {
        hipLaunchKernelGGL(conv4d_mfma_fb, dim3(D * D, 2), dim3(384), 0, stream,
                           x, W, out);
    }
}